// Round 1
// baseline (2244.019 us; speedup 1.0000x reference)
//
#include <hip/hip_runtime.h>

// ---------------------------------------------------------------------------
// GCN link prediction forward:
//   h = relu(Anorm @ (x@W1) + b1); z = Anorm @ (h@W2) + b2;
//   logits[e] = dot(z[a_e], z[b_e])
// Anorm includes self-loops + symmetric deg^-1/2 normalization.
// Refactor: pre-scale rows by inv_sqrt at the source, accumulate unscaled,
// apply inv_sqrt[d] at consumption. Self-loop = accumulator init.
// ---------------------------------------------------------------------------

__global__ void k_deg_init(float* __restrict__ deg, int n) {
    int i = blockIdx.x * blockDim.x + threadIdx.x;
    if (i < n) deg[i] = 1.0f;  // self-loop
}

__global__ void k_deg_count(const int* __restrict__ dst, float* __restrict__ deg, int E) {
    int i = blockIdx.x * blockDim.x + threadIdx.x;
    if (i < E) atomicAdd(&deg[dst[i]], 1.0f);
}

__global__ void k_inv(float* __restrict__ deg, int n) {
    int i = blockIdx.x * blockDim.x + threadIdx.x;
    if (i < n) deg[i] = rsqrtf(deg[i]);  // deg >= 1 always
}

// xws[n][32] = (x[n] @ W1) * inv[n]; acc1 initialized to the same (self-loop).
__global__ __launch_bounds__(256) void k_xw(const float* __restrict__ x,
                                            const float* __restrict__ W1,
                                            const float* __restrict__ inv,
                                            float* __restrict__ xws,
                                            float* __restrict__ acc1, int n) {
    __shared__ float W1s[128 * 32];   // 16 KB
    __shared__ float xsh[8 * 128];    // 4 KB, 8 rows/block
    int t = threadIdx.x;
#pragma unroll
    for (int i = 0; i < 16; ++i) W1s[i * 256 + t] = W1[i * 256 + t];
    int base = blockIdx.x * 8;
    if (base + 8 <= n) {
        ((float4*)xsh)[t] = ((const float4*)(x + (size_t)base * 128))[t];
    } else {
        for (int i = t; i < 8 * 128; i += 256) {
            int node = base + (i >> 7);
            xsh[i] = (node < n) ? x[(size_t)node * 128 + (i & 127)] : 0.0f;
        }
    }
    __syncthreads();
    int j = t & 31, r = t >> 5;
    int node = base + r;
    if (node >= n) return;
    float sum = 0.0f;
#pragma unroll
    for (int k = 0; k < 128; ++k) sum += xsh[r * 128 + k] * W1s[k * 32 + j];
    float v = sum * inv[node];
    xws[node * 32 + j]  = v;
    acc1[node * 32 + j] = v;
}

// 8 threads per edge, each handles 4 consecutive cols (float4 gather, 4 atomics).
__global__ void k_edge1(const int* __restrict__ src, const int* __restrict__ dst,
                        const float* __restrict__ xws, float* __restrict__ acc1, int E) {
    int tid = blockIdx.x * blockDim.x + threadIdx.x;
    if (tid >= E * 8) return;
    int e = tid >> 3, p = tid & 7;
    int s = src[e], d = dst[e];
    float4 v = ((const float4*)xws)[s * 8 + p];
    float* a = acc1 + (size_t)d * 32 + p * 4;
    atomicAdd(a + 0, v.x);
    atomicAdd(a + 1, v.y);
    atomicAdd(a + 2, v.z);
    atomicAdd(a + 3, v.w);
}

// h = relu(inv*acc1 + b1); hws[n][16] = (h @ W2) * inv[n]; acc2 init same.
__global__ __launch_bounds__(256) void k_hgemm(const float* __restrict__ acc1,
                                               const float* __restrict__ b1,
                                               const float* __restrict__ W2,
                                               const float* __restrict__ inv,
                                               float* __restrict__ hws,
                                               float* __restrict__ acc2, int n) {
    __shared__ float W2s[32 * 16];
    __shared__ float b1s[32];
    __shared__ float hsh[16 * 33];  // stride 33: avoid 4-way bank conflict
    int t = threadIdx.x;
    W2s[t]       = W2[t];
    W2s[256 + t] = W2[256 + t];
    if (t < 32) b1s[t] = b1[t];
    __syncthreads();
    int base = blockIdx.x * 16;
#pragma unroll
    for (int i = t; i < 512; i += 256) {
        int nl = i >> 5, kk = i & 31;
        int node = base + nl;
        float h = 0.0f;
        if (node < n) {
            h = inv[node] * acc1[(size_t)node * 32 + kk] + b1s[kk];
            h = fmaxf(h, 0.0f);
        }
        hsh[nl * 33 + kk] = h;
    }
    __syncthreads();
    int k = t & 15, r = t >> 4;
    int node = base + r;
    if (node >= n) return;
    float sum = 0.0f;
#pragma unroll
    for (int kk = 0; kk < 32; ++kk) sum += hsh[r * 33 + kk] * W2s[kk * 16 + k];
    float v = sum * inv[node];
    hws[node * 16 + k]  = v;
    acc2[node * 16 + k] = v;
}

// 4 threads per edge, 4 cols each.
__global__ void k_edge2(const int* __restrict__ src, const int* __restrict__ dst,
                        const float* __restrict__ hws, float* __restrict__ acc2, int E) {
    int tid = blockIdx.x * blockDim.x + threadIdx.x;
    if (tid >= E * 4) return;
    int e = tid >> 2, p = tid & 3;
    int s = src[e], d = dst[e];
    float4 v = ((const float4*)hws)[s * 4 + p];
    float* a = acc2 + (size_t)d * 16 + p * 4;
    atomicAdd(a + 0, v.x);
    atomicAdd(a + 1, v.y);
    atomicAdd(a + 2, v.z);
    atomicAdd(a + 3, v.w);
}

__global__ void k_z(const float* __restrict__ acc2, const float* __restrict__ inv,
                    const float* __restrict__ b2, float* __restrict__ z, int n) {
    int i = blockIdx.x * blockDim.x + threadIdx.x;
    if (i < n * 16) z[i] = inv[i >> 4] * acc2[i] + b2[i & 15];
}

__global__ void k_decode(const int* __restrict__ eli, const float* __restrict__ z,
                         float* __restrict__ out, int L) {
    int e = blockIdx.x * blockDim.x + threadIdx.x;
    if (e >= L) return;
    int a = eli[e], b = eli[L + e];
    const float4* za = (const float4*)(z + (size_t)a * 16);
    const float4* zb = (const float4*)(z + (size_t)b * 16);
    float s = 0.0f;
#pragma unroll
    for (int i = 0; i < 4; ++i) {
        float4 u = za[i], w = zb[i];
        s += u.x * w.x + u.y * w.y + u.z * w.z + u.w * w.w;
    }
    out[e] = s;
}

extern "C" void kernel_launch(void* const* d_in, const int* in_sizes, int n_in,
                              void* d_out, int out_size, void* d_ws, size_t ws_size,
                              hipStream_t stream) {
    const float* x   = (const float*)d_in[0];
    const int*   ei  = (const int*)d_in[1];
    const int*   eli = (const int*)d_in[2];
    const float* W1  = (const float*)d_in[3];
    const float* b1  = (const float*)d_in[4];
    const float* W2  = (const float*)d_in[5];
    const float* b2  = (const float*)d_in[6];
    float* out = (float*)d_out;

    int n = in_sizes[0] / 128;
    int E = in_sizes[1] / 2;
    int L = in_sizes[2] / 2;
    const int* src = ei;
    const int* dst = ei + E;

    // workspace layout (floats): inv | xws | acc1 | hws | acc2 | z  = n*113 floats
    float* ws   = (float*)d_ws;
    float* inv  = ws;
    float* xws  = inv  + n;
    float* acc1 = xws  + (size_t)n * 32;
    float* hws  = acc1 + (size_t)n * 32;
    float* acc2 = hws  + (size_t)n * 16;
    float* z    = acc2 + (size_t)n * 16;

    k_deg_init<<<(n + 255) / 256, 256, 0, stream>>>(inv, n);
    k_deg_count<<<(E + 255) / 256, 256, 0, stream>>>(dst, inv, E);
    k_inv<<<(n + 255) / 256, 256, 0, stream>>>(inv, n);
    k_xw<<<(n + 7) / 8, 256, 0, stream>>>(x, W1, inv, xws, acc1, n);
    k_edge1<<<(E * 8 + 255) / 256, 256, 0, stream>>>(src, dst, xws, acc1, E);
    k_hgemm<<<(n + 15) / 16, 256, 0, stream>>>(acc1, b1, W2, inv, hws, acc2, n);
    k_edge2<<<(E * 4 + 255) / 256, 256, 0, stream>>>(src, dst, hws, acc2, E);
    k_z<<<(n * 16 + 255) / 256, 256, 0, stream>>>(acc2, inv, b2, z, n);
    k_decode<<<(L + 255) / 256, 256, 0, stream>>>(eli, z, out, L);
}

// Round 2
// 783.048 us; speedup vs baseline: 2.8657x; 2.8657x over previous
//
#include <hip/hip_runtime.h>

// ---------------------------------------------------------------------------
// GCN link prediction forward, CSR/gather formulation (no fp32 atomics):
//   counting-sort edges by dst -> CSR; per-node wave gathers neighbor rows.
//   h = relu(inv*(xws[d] + sum_s xws[s]) + b1), xws = (x@W1)*inv
//   z = inv*(hws[d] + sum_s hws[s]) + b2,       hws = (h@W2)*inv
//   logits[e] = dot(z[a], z[b])
// ---------------------------------------------------------------------------

__global__ void k_zero(int* __restrict__ p, int n) {
    int i = blockIdx.x * blockDim.x + threadIdx.x;
    if (i < n) p[i] = 0;
}

__global__ void k_hist(const int* __restrict__ dst, int* __restrict__ hist, int E) {
    int i = blockIdx.x * blockDim.x + threadIdx.x;
    if (i < E) atomicAdd(&hist[dst[i]], 1);
}

// Per-block exclusive scan over chunks of 1024 (256 thr x 4), block sums out.
__global__ __launch_bounds__(256) void k_scan1(const int* __restrict__ hist,
                                               int* __restrict__ rp,
                                               int* __restrict__ bsum, int n) {
    __shared__ int sh[256];
    int t = threadIdx.x;
    int base = blockIdx.x * 1024 + t * 4;
    int v0 = (base + 0 < n) ? hist[base + 0] : 0;
    int v1 = (base + 1 < n) ? hist[base + 1] : 0;
    int v2 = (base + 2 < n) ? hist[base + 2] : 0;
    int v3 = (base + 3 < n) ? hist[base + 3] : 0;
    sh[t] = v0 + v1 + v2 + v3;
    __syncthreads();
    for (int off = 1; off < 256; off <<= 1) {
        int add = (t >= off) ? sh[t - off] : 0;
        __syncthreads();
        sh[t] += add;
        __syncthreads();
    }
    if (t == 255) bsum[blockIdx.x] = sh[255];
    int run = (t > 0) ? sh[t - 1] : 0;
    if (base + 0 < n) rp[base + 0] = run; run += v0;
    if (base + 1 < n) rp[base + 1] = run; run += v1;
    if (base + 2 < n) rp[base + 2] = run; run += v2;
    if (base + 3 < n) rp[base + 3] = run;
}

// Single-block exclusive scan of block sums (nb <= 256).
__global__ __launch_bounds__(256) void k_scan2(int* __restrict__ bsum,
                                               int* __restrict__ boff, int nb) {
    __shared__ int sh[256];
    int t = threadIdx.x;
    sh[t] = (t < nb) ? bsum[t] : 0;
    __syncthreads();
    for (int off = 1; off < 256; off <<= 1) {
        int add = (t >= off) ? sh[t - off] : 0;
        __syncthreads();
        sh[t] += add;
        __syncthreads();
    }
    if (t < nb) boff[t] = (t > 0) ? sh[t - 1] : 0;
}

// Finalize row_ptr, init cursors, compute inv_sqrt(deg) (deg = in-count + 1).
__global__ void k_scan3(int* __restrict__ rp, const int* __restrict__ boff,
                        const int* __restrict__ hist, int* __restrict__ cursor,
                        float* __restrict__ inv, int n, int E) {
    int i = blockIdx.x * blockDim.x + threadIdx.x;
    if (i < n) {
        int r = rp[i] + boff[i >> 10];
        rp[i] = r;
        cursor[i] = r;
        inv[i] = rsqrtf((float)(hist[i] + 1));
    }
    if (i == 0) rp[n] = E;
}

__global__ void k_scatter(const int* __restrict__ src, const int* __restrict__ dst,
                          int* __restrict__ cursor, int* __restrict__ col_src, int E) {
    int e = blockIdx.x * blockDim.x + threadIdx.x;
    if (e >= E) return;
    int pos = atomicAdd(&cursor[dst[e]], 1);
    col_src[pos] = src[e];
}

// xws[n][32] = (x[n] @ W1) * inv[n]
__global__ __launch_bounds__(256) void k_xw(const float* __restrict__ x,
                                            const float* __restrict__ W1,
                                            const float* __restrict__ inv,
                                            float* __restrict__ xws, int n) {
    __shared__ float W1s[128 * 32];   // 16 KB
    __shared__ float xsh[8 * 128];    // 4 KB, 8 rows/block
    int t = threadIdx.x;
#pragma unroll
    for (int i = 0; i < 16; ++i) W1s[i * 256 + t] = W1[i * 256 + t];
    int base = blockIdx.x * 8;
    if (base + 8 <= n) {
        ((float4*)xsh)[t] = ((const float4*)(x + (size_t)base * 128))[t];
    } else {
        for (int i = t; i < 8 * 128; i += 256) {
            int node = base + (i >> 7);
            xsh[i] = (node < n) ? x[(size_t)node * 128 + (i & 127)] : 0.0f;
        }
    }
    __syncthreads();
    int j = t & 31, r = t >> 5;
    int node = base + r;
    if (node >= n) return;
    float sum = 0.0f;
#pragma unroll
    for (int k = 0; k < 128; ++k) sum += xsh[r * 128 + k] * W1s[k * 32 + j];
    xws[(size_t)node * 32 + j] = sum * inv[node];
}

// One wave per node: h[d] = relu(inv[d]*(xws[d] + sum_neighbors xws[s]) + b1)
__global__ __launch_bounds__(256) void k_agg1(const int* __restrict__ rp,
                                              const int* __restrict__ cs,
                                              const float* __restrict__ xws,
                                              const float* __restrict__ inv,
                                              const float* __restrict__ b1,
                                              float* __restrict__ h, int n) {
    int w = (blockIdx.x * blockDim.x + threadIdx.x) >> 6;  // node = global wave id
    if (w >= n) return;
    int lane = threadIdx.x & 63;
    int col = lane & 31, g = lane >> 5;
    int beg = rp[w], end = rp[w + 1];
    float acc = (g == 0) ? xws[(size_t)w * 32 + col] : 0.0f;  // self-loop
    for (int i = beg + g; i < end; i += 2) {
        int s = cs[i];
        acc += xws[(size_t)s * 32 + col];
    }
    acc += __shfl_xor(acc, 32);
    if (g == 0) {
        float v = inv[w] * acc + b1[col];
        h[(size_t)w * 32 + col] = fmaxf(v, 0.0f);
    }
}

// hws[n][16] = (h @ W2) * inv[n]
__global__ __launch_bounds__(256) void k_hgemm(const float* __restrict__ h,
                                               const float* __restrict__ W2,
                                               const float* __restrict__ inv,
                                               float* __restrict__ hws, int n) {
    __shared__ float W2s[32 * 16];
    __shared__ float hsh[16 * 33];  // stride 33: avoid bank conflicts
    int t = threadIdx.x;
    W2s[t]       = W2[t];
    W2s[256 + t] = W2[256 + t];
    __syncthreads();
    int base = blockIdx.x * 16;
#pragma unroll
    for (int i = t; i < 512; i += 256) {
        int nl = i >> 5, kk = i & 31;
        int node = base + nl;
        hsh[nl * 33 + kk] = (node < n) ? h[(size_t)node * 32 + kk] : 0.0f;
    }
    __syncthreads();
    int k = t & 15, r = t >> 4;
    int node = base + r;
    if (node >= n) return;
    float sum = 0.0f;
#pragma unroll
    for (int kk = 0; kk < 32; ++kk) sum += hsh[r * 33 + kk] * W2s[kk * 16 + k];
    hws[(size_t)node * 16 + k] = sum * inv[node];
}

// One wave per node: z[d] = inv[d]*(hws[d] + sum_neighbors hws[s]) + b2
__global__ __launch_bounds__(256) void k_agg2(const int* __restrict__ rp,
                                              const int* __restrict__ cs,
                                              const float* __restrict__ hws,
                                              const float* __restrict__ inv,
                                              const float* __restrict__ b2,
                                              float* __restrict__ z, int n) {
    int w = (blockIdx.x * blockDim.x + threadIdx.x) >> 6;
    if (w >= n) return;
    int lane = threadIdx.x & 63;
    int col = lane & 15, g = lane >> 4;
    int beg = rp[w], end = rp[w + 1];
    float acc = (g == 0) ? hws[(size_t)w * 16 + col] : 0.0f;  // self-loop
    for (int i = beg + g; i < end; i += 4) {
        int s = cs[i];
        acc += hws[(size_t)s * 16 + col];
    }
    acc += __shfl_xor(acc, 32);
    acc += __shfl_xor(acc, 16);
    if (g == 0) z[(size_t)w * 16 + col] = inv[w] * acc + b2[col];
}

__global__ void k_decode(const int* __restrict__ eli, const float* __restrict__ z,
                         float* __restrict__ out, int L) {
    int e = blockIdx.x * blockDim.x + threadIdx.x;
    if (e >= L) return;
    int a = eli[e], b = eli[L + e];
    const float4* za = (const float4*)(z + (size_t)a * 16);
    const float4* zb = (const float4*)(z + (size_t)b * 16);
    float s = 0.0f;
#pragma unroll
    for (int i = 0; i < 4; ++i) {
        float4 u = za[i], w = zb[i];
        s += u.x * w.x + u.y * w.y + u.z * w.z + u.w * w.w;
    }
    out[e] = s;
}

extern "C" void kernel_launch(void* const* d_in, const int* in_sizes, int n_in,
                              void* d_out, int out_size, void* d_ws, size_t ws_size,
                              hipStream_t stream) {
    const float* x   = (const float*)d_in[0];
    const int*   ei  = (const int*)d_in[1];
    const int*   eli = (const int*)d_in[2];
    const float* W1  = (const float*)d_in[3];
    const float* b1  = (const float*)d_in[4];
    const float* W2  = (const float*)d_in[5];
    const float* b2  = (const float*)d_in[6];
    float* out = (float*)d_out;

    int n = in_sizes[0] / 128;
    int E = in_sizes[1] / 2;
    int L = in_sizes[2] / 2;
    const int* src = ei;
    const int* dst = ei + E;

    // workspace layout: floats [inv n | xws 32n | h 32n | hws 16n | z 16n]
    // then ints [col_src E | hist n | rp n+1 | cursor n | bsum 256 | boff 256]
    float* fws  = (float*)d_ws;
    float* inv  = fws;
    float* xws  = inv + n;
    float* h    = xws + (size_t)n * 32;
    float* hws  = h   + (size_t)n * 32;
    float* z    = hws + (size_t)n * 16;
    int* iws     = (int*)(z + (size_t)n * 16);
    int* col_src = iws;
    int* hist    = col_src + E;
    int* rp      = hist + n;
    int* cursor  = rp + n + 1;
    int* bsum    = cursor + n;
    int* boff    = bsum + 256;

    int nb = (n + 1023) / 1024;  // scan blocks (<=256 supported)

    k_zero<<<(n + 255) / 256, 256, 0, stream>>>(hist, n);
    k_hist<<<(E + 255) / 256, 256, 0, stream>>>(dst, hist, E);
    k_scan1<<<nb, 256, 0, stream>>>(hist, rp, bsum, n);
    k_scan2<<<1, 256, 0, stream>>>(bsum, boff, nb);
    k_scan3<<<(n + 255) / 256, 256, 0, stream>>>(rp, boff, hist, cursor, inv, n, E);
    k_scatter<<<(E + 255) / 256, 256, 0, stream>>>(src, dst, cursor, col_src, E);
    k_xw<<<(n + 7) / 8, 256, 0, stream>>>(x, W1, inv, xws, n);
    k_agg1<<<(n * 64 + 255) / 256, 256, 0, stream>>>(rp, col_src, xws, inv, b1, h, n);
    k_hgemm<<<(n + 15) / 16, 256, 0, stream>>>(h, W2, inv, hws, n);
    k_agg2<<<(n * 64 + 255) / 256, 256, 0, stream>>>(rp, col_src, hws, inv, b2, z, n);
    k_decode<<<(L + 255) / 256, 256, 0, stream>>>(eli, z, out, L);
}